// Round 7
// baseline (483.804 us; speedup 1.0000x reference)
//
#include <hip/hip_runtime.h>
#include <hip/hip_bf16.h>

// ---------------- problem constants ----------------
#define T_TOK 2048
#define H_DIM 1024
#define F_DIM 4096
#define E_NUM 16
#define K_TOP 4

typedef float    floatx4 __attribute__((ext_vector_type(4)));
typedef _Float16 f16x8   __attribute__((ext_vector_type(8)));
typedef _Float16 f16x4   __attribute__((ext_vector_type(4)));

// ---------------- ws layout (bytes) ----------------
#define MiB (1024ull * 1024ull)
#define LOGIT_OFF ((size_t)0)
#define OFFS_OFF  (256ull * 1024)
#define TOKS_OFF  (320ull * 1024)
#define WSL_OFF   (384ull * 1024)
#define STK_OFF   (448ull * 1024)
#define TILEE_OFF (512ull * 1024)
#define TILEM_OFF (TILEE_OFF + 512)
#define TILEC_OFF (TILEM_OFF + 512)
#define XH_OFF    (1ull * MiB)     // 4 MiB f16
#define HBUF_OFF  (8ull * MiB)     // 64 MiB f16 (hrf f32 8 MiB overlays start)
#define YBUF_OFF  (72ull * MiB)    // 16 MiB f16
#define W1T_OFF   (104ull * MiB)   // 128 MiB f16 [E][F][H]
#define W2T_OFF   (232ull * MiB)   // 128 MiB f16 [E][H][F]
#define WS_NEED_FAST (360ull * MiB)

// ---------------- helpers ----------------
__device__ __forceinline__ void gload16(const void* g, void* l) {
  __builtin_amdgcn_global_load_lds(
      (const __attribute__((address_space(1))) unsigned int*)g,
      (__attribute__((address_space(3))) unsigned int*)l, 16, 0, 0);
}

// fast GELU: tanh-form, hw exp
__device__ __forceinline__ float gelu_fast(float v) {
  float z = 0.7978845608028654f * (v + 0.044715f * v * v * v);
  float e = __expf(2.f * z);
  float t = 1.f - 2.f / (e + 1.f);
  return 0.5f * v * (1.f + t);
}

// ---------------- device bodies ----------------
__device__ __forceinline__ void cast_x_body(int blk, const float* __restrict__ x,
                                            _Float16* __restrict__ xh) {
  int i = blk * 256 + threadIdx.x;
  const floatx4* xin = reinterpret_cast<const floatx4*>(x) + (size_t)i * 2;
  floatx4 a = xin[0], b = xin[1];
  f16x8 o;
  o[0] = (_Float16)a[0]; o[1] = (_Float16)a[1]; o[2] = (_Float16)a[2]; o[3] = (_Float16)a[3];
  o[4] = (_Float16)b[0]; o[5] = (_Float16)b[1]; o[6] = (_Float16)b[2]; o[7] = (_Float16)b[3];
  *reinterpret_cast<f16x8*>(xh + (size_t)i * 8) = o;
}

// transpose-cast one 64x64 tile: W [z][K][N] f32 -> Wt [z][N][K] f16
__device__ __forceinline__ void tcast_body(const float* __restrict__ W,
                                           _Float16* __restrict__ Wt, int K, int N,
                                           int e, int k0, int n0, char* smem) {
  float (*Tt)[68] = (float(*)[68])smem;
  const float* We = W + (size_t)e * K * N;
  int t = threadIdx.x;
  int kk = t >> 4, nn = (t & 15) * 4;
#pragma unroll
  for (int j = 0; j < 4; j++) {
    int k = kk + 16 * j;
    floatx4 v = *reinterpret_cast<const floatx4*>(We + (size_t)(k0 + k) * N + n0 + nn);
    *reinterpret_cast<floatx4*>(&Tt[k][nn]) = v;
  }
  __syncthreads();
  int nr = t >> 2, kc = t & 3;
  f16x8 o0, o1;
#pragma unroll
  for (int j = 0; j < 8; j++) {
    o0[j] = (_Float16)Tt[kc * 16 + j][nr];
    o1[j] = (_Float16)Tt[kc * 16 + 8 + j][nr];
  }
  _Float16* dst = Wt + (size_t)e * N * K + (size_t)(n0 + nr) * K + k0 + kc * 16;
  *reinterpret_cast<f16x8*>(dst) = o0;
  *reinterpret_cast<f16x8*>(dst + 8) = o1;
}

// router GEMM1 64x64 tile, near-fp32 via 3-term fp16 split
__device__ __forceinline__ void router_gemm1_body(
    int m0, int n0, const float* __restrict__ x, const float* __restrict__ Wr1,
    const float* __restrict__ br1, float* __restrict__ hrf, char* smem) {
  _Float16 (*Ah)[40] = (_Float16(*)[40])(smem);
  _Float16 (*Al)[40] = (_Float16(*)[40])(smem + 5120);
  _Float16 (*Bh)[40] = (_Float16(*)[40])(smem + 10240);
  _Float16 (*Bl)[40] = (_Float16(*)[40])(smem + 15360);
  int tid = threadIdx.x;
  int arow = tid >> 2, achk = tid & 3;
  const float* Arow = x + (size_t)(m0 + arow) * H_DIM + achk * 8;
  int brow = tid >> 3, bq = tid & 7;

  floatx4 acc[2][2];
#pragma unroll
  for (int i = 0; i < 2; i++)
#pragma unroll
    for (int j = 0; j < 2; j++) acc[i][j] = (floatx4){0.f, 0.f, 0.f, 0.f};

  int wv = tid >> 6, lane = tid & 63;
  int wm = wv >> 1, wn = wv & 1;
  int lrow = lane & 15, lk = (lane >> 4) * 8;

  for (int k0 = 0; k0 < H_DIM; k0 += 32) {
    floatx4 a0 = *reinterpret_cast<const floatx4*>(Arow + k0);
    floatx4 a1 = *reinterpret_cast<const floatx4*>(Arow + k0 + 4);
    f16x8 hv, lv;
#pragma unroll
    for (int j = 0; j < 4; j++) {
      _Float16 hi = (_Float16)a0[j]; hv[j] = hi; lv[j] = (_Float16)(a0[j] - (float)hi);
      _Float16 hi2 = (_Float16)a1[j]; hv[4 + j] = hi2; lv[4 + j] = (_Float16)(a1[j] - (float)hi2);
    }
    *reinterpret_cast<f16x8*>(&Ah[arow][achk * 8]) = hv;
    *reinterpret_cast<f16x8*>(&Al[arow][achk * 8]) = lv;
    const float* wp = Wr1 + (size_t)(k0 + brow) * H_DIM + n0 + bq * 4;
    floatx4 w0 = *reinterpret_cast<const floatx4*>(wp);
    floatx4 w1 = *reinterpret_cast<const floatx4*>(wp + 32);
#pragma unroll
    for (int i = 0; i < 4; i++) {
      _Float16 h0 = (_Float16)w0[i];
      Bh[bq * 4 + i][brow] = h0; Bl[bq * 4 + i][brow] = (_Float16)(w0[i] - (float)h0);
      _Float16 h1 = (_Float16)w1[i];
      Bh[32 + bq * 4 + i][brow] = h1; Bl[32 + bq * 4 + i][brow] = (_Float16)(w1[i] - (float)h1);
    }
    __syncthreads();

    f16x8 ah0 = *reinterpret_cast<const f16x8*>(&Ah[32 * wm + lrow][lk]);
    f16x8 ah1 = *reinterpret_cast<const f16x8*>(&Ah[32 * wm + 16 + lrow][lk]);
    f16x8 al0 = *reinterpret_cast<const f16x8*>(&Al[32 * wm + lrow][lk]);
    f16x8 al1 = *reinterpret_cast<const f16x8*>(&Al[32 * wm + 16 + lrow][lk]);
    f16x8 bh0 = *reinterpret_cast<const f16x8*>(&Bh[32 * wn + lrow][lk]);
    f16x8 bh1 = *reinterpret_cast<const f16x8*>(&Bh[32 * wn + 16 + lrow][lk]);
    f16x8 bl0 = *reinterpret_cast<const f16x8*>(&Bl[32 * wn + lrow][lk]);
    f16x8 bl1 = *reinterpret_cast<const f16x8*>(&Bl[32 * wn + 16 + lrow][lk]);

    acc[0][0] = __builtin_amdgcn_mfma_f32_16x16x32_f16(ah0, bh0, acc[0][0], 0, 0, 0);
    acc[0][0] = __builtin_amdgcn_mfma_f32_16x16x32_f16(ah0, bl0, acc[0][0], 0, 0, 0);
    acc[0][0] = __builtin_amdgcn_mfma_f32_16x16x32_f16(al0, bh0, acc[0][0], 0, 0, 0);
    acc[0][1] = __builtin_amdgcn_mfma_f32_16x16x32_f16(ah0, bh1, acc[0][1], 0, 0, 0);
    acc[0][1] = __builtin_amdgcn_mfma_f32_16x16x32_f16(ah0, bl1, acc[0][1], 0, 0, 0);
    acc[0][1] = __builtin_amdgcn_mfma_f32_16x16x32_f16(al0, bh1, acc[0][1], 0, 0, 0);
    acc[1][0] = __builtin_amdgcn_mfma_f32_16x16x32_f16(ah1, bh0, acc[1][0], 0, 0, 0);
    acc[1][0] = __builtin_amdgcn_mfma_f32_16x16x32_f16(ah1, bl0, acc[1][0], 0, 0, 0);
    acc[1][0] = __builtin_amdgcn_mfma_f32_16x16x32_f16(al1, bh0, acc[1][0], 0, 0, 0);
    acc[1][1] = __builtin_amdgcn_mfma_f32_16x16x32_f16(ah1, bh1, acc[1][1], 0, 0, 0);
    acc[1][1] = __builtin_amdgcn_mfma_f32_16x16x32_f16(ah1, bl1, acc[1][1], 0, 0, 0);
    acc[1][1] = __builtin_amdgcn_mfma_f32_16x16x32_f16(al1, bh1, acc[1][1], 0, 0, 0);
    __syncthreads();
  }

#pragma unroll
  for (int am = 0; am < 2; am++) {
#pragma unroll
    for (int bn = 0; bn < 2; bn++) {
      int col = n0 + 32 * wn + 16 * bn + lrow;
      float bv = br1[col];
#pragma unroll
      for (int r = 0; r < 4; r++) {
        int rowt = 32 * wm + 16 * am + (lane >> 4) * 4 + r;
        float v = acc[am][bn][r] + bv;
        hrf[(size_t)(m0 + rowt) * H_DIM + col] = fmaxf(v, 0.f);
      }
    }
  }
}

// ---------- fused A (INTERLEAVED): 512 groups x 35 = {1 router, 2 cast_x, 32 tcastW1} --------
__global__ __launch_bounds__(256) void fusedA_kernel(
    const float* __restrict__ x, const float* __restrict__ Wr1, const float* __restrict__ br1,
    float* __restrict__ hrf, const float* __restrict__ W1, _Float16* __restrict__ W1t,
    _Float16* __restrict__ xh) {
  __shared__ __align__(16) char smem[20480];
  int g = blockIdx.x / 35, s = blockIdx.x % 35;
  if (s == 0) {
    // router tile g of 512: 32 m-tiles x 16 n-tiles
    router_gemm1_body((g >> 4) * 64, (g & 15) * 64, x, Wr1, br1, hrf, smem);
  } else if (s <= 2) {
    cast_x_body(g * 2 + (s - 1), x, xh);
  } else {
    int idx = g * 32 + (s - 3);     // 16384 tcast tiles of W1 (K=H, N=F)
    int nt = idx & 63, kt = (idx >> 6) & 15, e = idx >> 10;
    tcast_body(W1, W1t, H_DIM, F_DIM, e, kt * 64, nt * 64, smem);
  }
}

// logits = hrf @ Wr2 + br2 ; one wave per token (fp32)
__global__ __launch_bounds__(256) void router_logits_kernel(
    const float* __restrict__ hrf, const float* __restrict__ Wr2,
    const float* __restrict__ br2, float* __restrict__ logits) {
  int t = blockIdx.x * 4 + (threadIdx.x >> 6);
  int lane = threadIdx.x & 63;
  float acc[E_NUM];
#pragma unroll
  for (int e = 0; e < E_NUM; e++) acc[e] = 0.f;
  const float* hr = hrf + (size_t)t * H_DIM;
#pragma unroll 4
  for (int i = 0; i < H_DIM / 64; i++) {
    int k = lane + 64 * i;
    float a = hr[k];
    const floatx4* w4 = reinterpret_cast<const floatx4*>(Wr2 + (size_t)k * E_NUM);
    floatx4 w0 = w4[0], w1 = w4[1], w2 = w4[2], w3 = w4[3];
#pragma unroll
    for (int j = 0; j < 4; j++) {
      acc[j]      += a * w0[j];
      acc[4 + j]  += a * w1[j];
      acc[8 + j]  += a * w2[j];
      acc[12 + j] += a * w3[j];
    }
  }
#pragma unroll
  for (int e = 0; e < E_NUM; e++) {
    float v = acc[e];
    for (int off = 32; off > 0; off >>= 1) v += __shfl_xor(v, off);
    if (lane == e) logits[(size_t)t * E_NUM + e] = v + br2[e];
  }
}

// merged top-k + softmax + scan + tile table + scatter; one block of 1024 threads
__global__ __launch_bounds__(1024) void routing_kernel(
    const float* __restrict__ logits, int* __restrict__ offs,
    int* __restrict__ toks, float* __restrict__ wsl, int* __restrict__ stk,
    int* __restrict__ tileE, int* __restrict__ tileM, int* __restrict__ tileC) {
  __shared__ int cnt[E_NUM], cur[E_NUM], loff[E_NUM + 1];
  int tid = threadIdx.x;
  if (tid < E_NUM) { cnt[tid] = 0; cur[tid] = 0; }
  __syncthreads();
  int ti[2][K_TOP]; float tw[2][K_TOP];
#pragma unroll
  for (int u = 0; u < 2; u++) {
    int t = u * 1024 + tid;
    float lg[E_NUM];
#pragma unroll
    for (int e = 0; e < E_NUM; e++) lg[e] = logits[(size_t)t * E_NUM + e];
    unsigned int used = 0;
    float vals[K_TOP];
#pragma unroll
    for (int k = 0; k < K_TOP; k++) {
      float best = -1e30f; int bi = 0;
#pragma unroll
      for (int e = 0; e < E_NUM; e++) {
        if (!((used >> e) & 1u) && lg[e] > best) { best = lg[e]; bi = e; }
      }
      used |= (1u << bi);
      vals[k] = best; ti[u][k] = bi;
    }
    float m = vals[0], s = 0.f;
#pragma unroll
    for (int k = 0; k < K_TOP; k++) { tw[u][k] = expf(vals[k] - m); s += tw[u][k]; }
    float inv = 1.f / s;
#pragma unroll
    for (int k = 0; k < K_TOP; k++) {
      tw[u][k] *= inv;
      atomicAdd(&cnt[ti[u][k]], 1);
    }
  }
  __syncthreads();
  if (tid == 0) {
    int acc = 0;
    loff[0] = 0; offs[0] = 0;
    for (int e = 0; e < E_NUM; e++) { acc += cnt[e]; loff[e + 1] = acc; offs[e + 1] = acc; }
    int idx = 0;
    for (int e = 0; e < E_NUM; e++) {
      for (int m0 = 0; m0 < cnt[e]; m0 += 128) { tileE[idx] = e; tileM[idx] = m0; idx++; }
    }
    tileC[0] = idx;
  }
  __syncthreads();
#pragma unroll
  for (int u = 0; u < 2; u++) {
    int t = u * 1024 + tid;
#pragma unroll
    for (int k = 0; k < K_TOP; k++) {
      int e = ti[u][k];
      int pos = atomicAdd(&cur[e], 1);
      int slot = loff[e] + pos;
      toks[slot] = t;
      wsl[slot] = tw[u][k];
      stk[t * K_TOP + k] = slot;
    }
  }
}

// out[t][h] = sum_k ybuf[stk[t][k]][h] ; ybuf f16
__global__ void combine_kernel(const _Float16* __restrict__ ybuf, const int* __restrict__ stk,
                               float* __restrict__ out) {
  int i = blockIdx.x * 256 + threadIdx.x;
  size_t p = (size_t)i * 8;
  int t = (int)(p >> 10);
  int h = (int)(p & 1023);
  float s[8] = {0.f, 0.f, 0.f, 0.f, 0.f, 0.f, 0.f, 0.f};
#pragma unroll
  for (int k = 0; k < K_TOP; k++) {
    int slot = stk[t * K_TOP + k];
    f16x8 v = *reinterpret_cast<const f16x8*>(ybuf + (size_t)slot * H_DIM + h);
#pragma unroll
    for (int j = 0; j < 8; j++) s[j] += (float)v[j];
  }
  floatx4 o0 = {s[0], s[1], s[2], s[3]};
  floatx4 o1 = {s[4], s[5], s[6], s[7]};
  *reinterpret_cast<floatx4*>(out + p) = o0;
  *reinterpret_cast<floatx4*>(out + p + 4) = o1;
}

// ---------------- expert GEMM body: 128x128, 3-buffer counted-vmcnt, swizzled LDS ----------
template <int KK, int ACT, bool GATHER, bool SCALE>
__device__ __forceinline__ void moe_gemm_body(
    int ti, int n0, const _Float16* __restrict__ A, const _Float16* __restrict__ Bt,
    const float* __restrict__ bias, _Float16* __restrict__ Out,
    const int* __restrict__ offsets, const int* __restrict__ toklist,
    const float* __restrict__ wslot, const int* __restrict__ tileE,
    const int* __restrict__ tileM, const int* __restrict__ tileC,
    int N, char* smem) {
  if (ti >= tileC[0]) return;
  const int K = KK;
  int e = tileE[ti], m0 = tileM[ti];
  int base = offsets[e], cnt = offsets[e + 1] - base;

  _Float16 (*As)[128][32] = reinterpret_cast<_Float16(*)[128][32]>(smem);
  _Float16 (*Bs)[128][32] = reinterpret_cast<_Float16(*)[128][32]>(smem + 24576);

  int tid = threadIdx.x;
  int w = tid >> 6, lane = tid & 63;
  int wm = w >> 1, wn = w & 1;
  int lrow = lane & 15;

  int ar0 = w * 32 + (lane >> 2);
  int ar1 = ar0 + 16;
  int ach = (((lane & 3) ^ ((lane >> 3) & 3))) * 8;
  int mr0 = m0 + ar0; if (mr0 >= cnt) mr0 = cnt - 1;
  int mr1 = m0 + ar1; if (mr1 >= cnt) mr1 = cnt - 1;
  const _Float16* gA0 = A + (long)(GATHER ? toklist[base + mr0] : (base + mr0)) * K + ach;
  const _Float16* gA1 = A + (long)(GATHER ? toklist[base + mr1] : (base + mr1)) * K + ach;
  const _Float16* bge = Bt + (size_t)e * N * K;
  const _Float16* gB0 = bge + (long)(n0 + ar0) * K + ach;
  const _Float16* gB1 = bge + (long)(n0 + ar1) * K + ach;

  int phys8 = ((lane >> 4) ^ ((lrow >> 1) & 3)) * 8;

#define STAGE3(buf, kk) do { \
    gload16(gA0 + (kk), &As[buf][w * 32][0]); \
    gload16(gA1 + (kk), &As[buf][w * 32 + 16][0]); \
    gload16(gB0 + (kk), &Bs[buf][w * 32][0]); \
    gload16(gB1 + (kk), &Bs[buf][w * 32 + 16][0]); \
  } while (0)

#define COMPUTE3(buf) do { \
    f16x8 a[4], b[4]; \
    _Pragma("unroll") \
    for (int i = 0; i < 4; i++) { \
      a[i] = *reinterpret_cast<const f16x8*>(&As[buf][wm * 64 + i * 16 + lrow][phys8]); \
      b[i] = *reinterpret_cast<const f16x8*>(&Bs[buf][wn * 64 + i * 16 + lrow][phys8]); \
    } \
    __builtin_amdgcn_s_setprio(1); \
    _Pragma("unroll") \
    for (int i = 0; i < 4; i++) \
      _Pragma("unroll") \
      for (int j = 0; j < 4; j++) \
        acc[i][j] = __builtin_amdgcn_mfma_f32_16x16x32_f16(a[i], b[j], acc[i][j], 0, 0, 0); \
    __builtin_amdgcn_s_setprio(0); \
  } while (0)

  floatx4 acc[4][4];
#pragma unroll
  for (int i = 0; i < 4; i++)
#pragma unroll
    for (int j = 0; j < 4; j++) acc[i][j] = (floatx4){0.f, 0.f, 0.f, 0.f};

  constexpr int nk = KK / 32;
  STAGE3(0, 0);
  STAGE3(1, 32);

#pragma unroll 3
  for (int it = 0; it < nk - 1; ++it) {
    asm volatile("s_waitcnt vmcnt(4)" ::: "memory");
    __builtin_amdgcn_s_barrier();
    if (it + 2 < nk) STAGE3((it + 2) % 3, (it + 2) * 32);
    COMPUTE3(it % 3);
  }
  asm volatile("s_waitcnt vmcnt(0)" ::: "memory");
  __builtin_amdgcn_s_barrier();
  COMPUTE3((nk - 1) % 3);

#undef STAGE3
#undef COMPUTE3

  const float* be = bias + (size_t)e * N;
#pragma unroll
  for (int fm = 0; fm < 4; fm++) {
#pragma unroll
    for (int fn = 0; fn < 4; fn++) {
      int col = n0 + wn * 64 + fn * 16 + lrow;
      float bv = be[col];
#pragma unroll
      for (int r = 0; r < 4; r++) {
        int rowt = wm * 64 + fm * 16 + (lane >> 4) * 4 + r;
        int mg = m0 + rowt;
        if (mg < cnt) {
          float v = acc[fm][fn][r] + bv;
          if (ACT == 2) v = gelu_fast(v);
          long orow = base + mg;
          if (SCALE) v *= wslot[orow];
          Out[orow * (long)N + col] = (_Float16)v;
        }
      }
    }
  }
}

// ---------- fused B (INTERLEAVED): 256 groups x 74 = {10 GEMM1, 64 tcastW2} ----------
#define FB_TOTAL (256 * 74)
__global__ __launch_bounds__(256) void fusedB_kernel(
    const _Float16* __restrict__ xh, const _Float16* __restrict__ W1t,
    const float* __restrict__ b1, _Float16* __restrict__ hbuf,
    const int* __restrict__ offsets, const int* __restrict__ toklist,
    const int* __restrict__ tileE, const int* __restrict__ tileM, const int* __restrict__ tileC,
    const float* __restrict__ W2, _Float16* __restrict__ W2t) {
  __shared__ __align__(16) char smem[49152];
  int g = blockIdx.x / 74, s = blockIdx.x % 74;
  if (s < 10) {
    int idx = g * 10 + s;           // 2560 GEMM1 blocks: 80 m-tiles x 32 n-tiles
    moe_gemm_body<H_DIM, 2, true, false>(idx >> 5, (idx & 31) * 128, xh, W1t, b1, hbuf,
                                         offsets, toklist, nullptr, tileE, tileM, tileC,
                                         F_DIM, smem);
  } else {
    int idx = g * 64 + (s - 10);    // 16384 tcast tiles of W2 (K=F, N=H)
    int nt = idx & 15, kt = (idx >> 4) & 63, e = idx >> 10;
    tcast_body(W2, W2t, F_DIM, H_DIM, e, kt * 64, nt * 64, smem);
  }
}

// expert GEMM2 standalone (K=4096), f16 out with combine-weight scale
__global__ __launch_bounds__(256) void moe_gemm2_kernel(
    const _Float16* __restrict__ hbuf, const _Float16* __restrict__ W2t,
    const float* __restrict__ b2, _Float16* __restrict__ ybuf,
    const int* __restrict__ offsets, const float* __restrict__ wslot,
    const int* __restrict__ tileE, const int* __restrict__ tileM, const int* __restrict__ tileC) {
  __shared__ __align__(16) char smem[49152];
  moe_gemm_body<F_DIM, 0, false, true>(blockIdx.y, blockIdx.x * 128, hbuf, W2t, b2, ybuf,
                                       offsets, nullptr, wslot, tileE, tileM, tileC,
                                       H_DIM, smem);
}

// ---------------- FALLBACK MFMA GEMM (in-flight convert, small ws) ----------------
template <int ACT, bool GATHER, bool OFFS, bool SCALE>
__global__ __launch_bounds__(256) void moe_gemm(
    const _Float16* __restrict__ A, const float* __restrict__ W,
    const float* __restrict__ bias, _Float16* __restrict__ Out,
    const int* __restrict__ offsets, const int* __restrict__ toklist,
    const float* __restrict__ wslot, int M, int N, int K) {
  int e = blockIdx.z;
  int base = 0, cnt = M;
  if (OFFS) { base = offsets[e]; cnt = offsets[e + 1] - base; }
  int m0 = blockIdx.y * 64;
  if (m0 >= cnt) return;
  int n0 = blockIdx.x * 64;
  const float* We = W + (size_t)e * K * N;
  const float* be = bias + (size_t)e * N;

  __shared__ _Float16 As[64][40];
  __shared__ _Float16 Bs[64][40];

  int tid = threadIdx.x;
  int arow = tid >> 2, achk = tid & 3;
  int am_idx = m0 + arow; if (am_idx > cnt - 1) am_idx = cnt - 1;
  long arowg = GATHER ? (long)toklist[base + am_idx] : (long)(base + am_idx);
  const _Float16* Arow = A + arowg * (long)K + achk * 8;

  int brow = tid >> 3, bq = tid & 7;

  floatx4 acc[2][2];
#pragma unroll
  for (int i = 0; i < 2; i++)
#pragma unroll
    for (int j = 0; j < 2; j++) acc[i][j] = (floatx4){0.f, 0.f, 0.f, 0.f};

  int wv = tid >> 6, lane = tid & 63;
  int wm = wv >> 1, wn = wv & 1;
  int lrow = lane & 15, lk = (lane >> 4) * 8;

  for (int k0 = 0; k0 < K; k0 += 32) {
    *reinterpret_cast<f16x8*>(&As[arow][achk * 8]) = *reinterpret_cast<const f16x8*>(Arow + k0);
    const float* wp = We + (size_t)(k0 + brow) * N + n0 + bq * 4;
    floatx4 w0 = *reinterpret_cast<const floatx4*>(wp);
    floatx4 w1 = *reinterpret_cast<const floatx4*>(wp + 32);
#pragma unroll
    for (int i = 0; i < 4; i++) {
      Bs[bq * 4 + i][brow]      = (_Float16)w0[i];
      Bs[32 + bq * 4 + i][brow] = (_Float16)w1[i];
    }
    __syncthreads();

    f16x8 a0 = *reinterpret_cast<const f16x8*>(&As[32 * wm + lrow][lk]);
    f16x8 a1 = *reinterpret_cast<const f16x8*>(&As[32 * wm + 16 + lrow][lk]);
    f16x8 b0 = *reinterpret_cast<const f16x8*>(&Bs[32 * wn + lrow][lk]);
    f16x8 b1 = *reinterpret_cast<const f16x8*>(&Bs[32 * wn + 16 + lrow][lk]);
    acc[0][0] = __builtin_amdgcn_mfma_f32_16x16x32_f16(a0, b0, acc[0][0], 0, 0, 0);
    acc[0][1] = __builtin_amdgcn_mfma_f32_16x16x32_f16(a0, b1, acc[0][1], 0, 0, 0);
    acc[1][0] = __builtin_amdgcn_mfma_f32_16x16x32_f16(a1, b0, acc[1][0], 0, 0, 0);
    acc[1][1] = __builtin_amdgcn_mfma_f32_16x16x32_f16(a1, b1, acc[1][1], 0, 0, 0);
    __syncthreads();
  }

#pragma unroll
  for (int am = 0; am < 2; am++) {
#pragma unroll
    for (int bn = 0; bn < 2; bn++) {
      int col = n0 + 32 * wn + 16 * bn + lrow;
      float bv = be[col];
#pragma unroll
      for (int r = 0; r < 4; r++) {
        int rowt = 32 * wm + 16 * am + (lane >> 4) * 4 + r;
        int mg = m0 + rowt;
        if (mg < cnt) {
          float v = acc[am][bn][r] + bv;
          if (ACT == 2) v = gelu_fast(v);
          long orow = base + mg;
          if (SCALE) v *= wslot[orow];
          Out[orow * (long)N + col] = (_Float16)v;
        }
      }
    }
  }
}

__global__ void cast_x_kernel(const float* __restrict__ x, _Float16* __restrict__ xh) {
  cast_x_body(blockIdx.x, x, xh);
}

__global__ __launch_bounds__(256) void router_gemm1_kernel(
    const float* __restrict__ x, const float* __restrict__ Wr1,
    const float* __restrict__ br1, float* __restrict__ hrf) {
  __shared__ __align__(16) char smem[20480];
  router_gemm1_body(blockIdx.y * 64, blockIdx.x * 64, x, Wr1, br1, hrf, smem);
}

// ---------------- launch ----------------
extern "C" void kernel_launch(void* const* d_in, const int* in_sizes, int n_in,
                              void* d_out, int out_size, void* d_ws, size_t ws_size,
                              hipStream_t stream) {
  const float* x   = (const float*)d_in[0];
  const float* Wr1 = (const float*)d_in[1];
  const float* br1 = (const float*)d_in[2];
  const float* Wr2 = (const float*)d_in[3];
  const float* br2 = (const float*)d_in[4];
  const float* W1  = (const float*)d_in[5];
  const float* b1  = (const float*)d_in[6];
  const float* W2  = (const float*)d_in[7];
  const float* b2  = (const float*)d_in[8];
  float* out = (float*)d_out;

  char* ws = (char*)d_ws;
  float* logits = (float*)(ws + LOGIT_OFF);
  int*   offs   = (int*)(ws + OFFS_OFF);
  int*   toks   = (int*)(ws + TOKS_OFF);
  float* wsl    = (float*)(ws + WSL_OFF);
  int*   stk    = (int*)(ws + STK_OFF);
  int*   tileE  = (int*)(ws + TILEE_OFF);
  int*   tileM  = (int*)(ws + TILEM_OFF);
  int*   tileC  = (int*)(ws + TILEC_OFF);
  _Float16* xh   = (_Float16*)(ws + XH_OFF);
  float*    hrf  = (float*)(ws + HBUF_OFF);
  _Float16* hbuf = (_Float16*)(ws + HBUF_OFF);
  _Float16* ybuf = (_Float16*)(ws + YBUF_OFF);
  _Float16* W1t  = (_Float16*)(ws + W1T_OFF);
  _Float16* W2t  = (_Float16*)(ws + W2T_OFF);

  bool fast = ws_size >= WS_NEED_FAST;

  if (fast) {
    fusedA_kernel<<<512 * 35, 256, 0, stream>>>(x, Wr1, br1, hrf, W1, W1t, xh);
  } else {
    cast_x_kernel<<<(T_TOK * H_DIM / 8) / 256, 256, 0, stream>>>(x, xh);
    router_gemm1_kernel<<<dim3(H_DIM / 64, T_TOK / 64), 256, 0, stream>>>(x, Wr1, br1, hrf);
  }

  router_logits_kernel<<<T_TOK / 4, 256, 0, stream>>>(hrf, Wr2, br2, logits);
  routing_kernel<<<1, 1024, 0, stream>>>(logits, offs, toks, wsl, stk, tileE, tileM, tileC);

  if (fast) {
    fusedB_kernel<<<FB_TOTAL, 256, 0, stream>>>(xh, W1t, b1, hbuf, offs, toks,
                                                tileE, tileM, tileC, W2, W2t);
    moe_gemm2_kernel<<<dim3(H_DIM / 128, 80), 256, 0, stream>>>(hbuf, W2t, b2, ybuf, offs, wsl,
                                                                tileE, tileM, tileC);
  } else {
    moe_gemm<2, true, true, false><<<dim3(F_DIM / 64, T_TOK / 64, E_NUM), 256, 0, stream>>>(
        xh, W1, b1, hbuf, offs, toks, nullptr, T_TOK, F_DIM, H_DIM);
    moe_gemm<0, false, true, true><<<dim3(H_DIM / 64, T_TOK / 64, E_NUM), 256, 0, stream>>>(
        hbuf, W2, b2, ybuf, offs, nullptr, wsl, T_TOK, H_DIM, F_DIM);
  }

  combine_kernel<<<(T_TOK * H_DIM / 8) / 256, 256, 0, stream>>>(ybuf, stk, out);
}

// Round 8
// 476.580 us; speedup vs baseline: 1.0152x; 1.0152x over previous
//
#include <hip/hip_runtime.h>
#include <hip/hip_bf16.h>

// ---------------- problem constants ----------------
#define T_TOK 2048
#define H_DIM 1024
#define F_DIM 4096
#define E_NUM 16
#define K_TOP 4

typedef float    floatx4 __attribute__((ext_vector_type(4)));
typedef _Float16 f16x8   __attribute__((ext_vector_type(8)));
typedef _Float16 f16x4   __attribute__((ext_vector_type(4)));

// ---------------- ws layout (bytes) ----------------
#define MiB (1024ull * 1024ull)
#define LOGIT_OFF ((size_t)0)
#define OFFS_OFF  (256ull * 1024)
#define TOKS_OFF  (320ull * 1024)
#define WSL_OFF   (384ull * 1024)
#define STK_OFF   (448ull * 1024)
#define TILEE_OFF (512ull * 1024)
#define TILEM_OFF (TILEE_OFF + 512)
#define TILEC_OFF (TILEM_OFF + 512)
#define XH_OFF    (1ull * MiB)     // 4 MiB f16
#define HBUF_OFF  (8ull * MiB)     // 64 MiB f16 (hrf f32 8 MiB overlays start)
#define YBUF_OFF  (72ull * MiB)    // 16 MiB f16
#define W1T_OFF   (104ull * MiB)   // 128 MiB f16 [E][F][H]
#define W2T_OFF   (232ull * MiB)   // 128 MiB f16 [E][H][F]
#define WS_NEED_FAST (360ull * MiB)

// ---------------- helpers ----------------
__device__ __forceinline__ void gload16(const void* g, void* l) {
  __builtin_amdgcn_global_load_lds(
      (const __attribute__((address_space(1))) unsigned int*)g,
      (__attribute__((address_space(3))) unsigned int*)l, 16, 0, 0);
}

// fast GELU: tanh-form, hw exp
__device__ __forceinline__ float gelu_fast(float v) {
  float z = 0.7978845608028654f * (v + 0.044715f * v * v * v);
  float e = __expf(2.f * z);
  float t = 1.f - 2.f / (e + 1.f);
  return 0.5f * v * (1.f + t);
}

// ---------------- device bodies ----------------
__device__ __forceinline__ void cast_x_body(int blk, const float* __restrict__ x,
                                            _Float16* __restrict__ xh) {
  int i = blk * 256 + threadIdx.x;
  const floatx4* xin = reinterpret_cast<const floatx4*>(x) + (size_t)i * 2;
  floatx4 a = xin[0], b = xin[1];
  f16x8 o;
  o[0] = (_Float16)a[0]; o[1] = (_Float16)a[1]; o[2] = (_Float16)a[2]; o[3] = (_Float16)a[3];
  o[4] = (_Float16)b[0]; o[5] = (_Float16)b[1]; o[6] = (_Float16)b[2]; o[7] = (_Float16)b[3];
  *reinterpret_cast<f16x8*>(xh + (size_t)i * 8) = o;
}

// transpose-cast one 64x64 tile: W [z][K][N] f32 -> Wt [z][N][K] f16
__device__ __forceinline__ void tcast_body(const float* __restrict__ W,
                                           _Float16* __restrict__ Wt, int K, int N,
                                           int e, int k0, int n0, char* smem) {
  float (*Tt)[68] = (float(*)[68])smem;
  const float* We = W + (size_t)e * K * N;
  int t = threadIdx.x;
  int kk = t >> 4, nn = (t & 15) * 4;
#pragma unroll
  for (int j = 0; j < 4; j++) {
    int k = kk + 16 * j;
    floatx4 v = *reinterpret_cast<const floatx4*>(We + (size_t)(k0 + k) * N + n0 + nn);
    *reinterpret_cast<floatx4*>(&Tt[k][nn]) = v;
  }
  __syncthreads();
  int nr = t >> 2, kc = t & 3;
  f16x8 o0, o1;
#pragma unroll
  for (int j = 0; j < 8; j++) {
    o0[j] = (_Float16)Tt[kc * 16 + j][nr];
    o1[j] = (_Float16)Tt[kc * 16 + 8 + j][nr];
  }
  _Float16* dst = Wt + (size_t)e * N * K + (size_t)(n0 + nr) * K + k0 + kc * 16;
  *reinterpret_cast<f16x8*>(dst) = o0;
  *reinterpret_cast<f16x8*>(dst + 8) = o1;
}

// router GEMM1 64x64 tile, near-fp32 via 3-term fp16 split
__device__ __forceinline__ void router_gemm1_body(
    int m0, int n0, const float* __restrict__ x, const float* __restrict__ Wr1,
    const float* __restrict__ br1, float* __restrict__ hrf, char* smem) {
  _Float16 (*Ah)[40] = (_Float16(*)[40])(smem);
  _Float16 (*Al)[40] = (_Float16(*)[40])(smem + 5120);
  _Float16 (*Bh)[40] = (_Float16(*)[40])(smem + 10240);
  _Float16 (*Bl)[40] = (_Float16(*)[40])(smem + 15360);
  int tid = threadIdx.x;
  int arow = tid >> 2, achk = tid & 3;
  const float* Arow = x + (size_t)(m0 + arow) * H_DIM + achk * 8;
  int brow = tid >> 3, bq = tid & 7;

  floatx4 acc[2][2];
#pragma unroll
  for (int i = 0; i < 2; i++)
#pragma unroll
    for (int j = 0; j < 2; j++) acc[i][j] = (floatx4){0.f, 0.f, 0.f, 0.f};

  int wv = tid >> 6, lane = tid & 63;
  int wm = wv >> 1, wn = wv & 1;
  int lrow = lane & 15, lk = (lane >> 4) * 8;

  for (int k0 = 0; k0 < H_DIM; k0 += 32) {
    floatx4 a0 = *reinterpret_cast<const floatx4*>(Arow + k0);
    floatx4 a1 = *reinterpret_cast<const floatx4*>(Arow + k0 + 4);
    f16x8 hv, lv;
#pragma unroll
    for (int j = 0; j < 4; j++) {
      _Float16 hi = (_Float16)a0[j]; hv[j] = hi; lv[j] = (_Float16)(a0[j] - (float)hi);
      _Float16 hi2 = (_Float16)a1[j]; hv[4 + j] = hi2; lv[4 + j] = (_Float16)(a1[j] - (float)hi2);
    }
    *reinterpret_cast<f16x8*>(&Ah[arow][achk * 8]) = hv;
    *reinterpret_cast<f16x8*>(&Al[arow][achk * 8]) = lv;
    const float* wp = Wr1 + (size_t)(k0 + brow) * H_DIM + n0 + bq * 4;
    floatx4 w0 = *reinterpret_cast<const floatx4*>(wp);
    floatx4 w1 = *reinterpret_cast<const floatx4*>(wp + 32);
#pragma unroll
    for (int i = 0; i < 4; i++) {
      _Float16 h0 = (_Float16)w0[i];
      Bh[bq * 4 + i][brow] = h0; Bl[bq * 4 + i][brow] = (_Float16)(w0[i] - (float)h0);
      _Float16 h1 = (_Float16)w1[i];
      Bh[32 + bq * 4 + i][brow] = h1; Bl[32 + bq * 4 + i][brow] = (_Float16)(w1[i] - (float)h1);
    }
    __syncthreads();

    f16x8 ah0 = *reinterpret_cast<const f16x8*>(&Ah[32 * wm + lrow][lk]);
    f16x8 ah1 = *reinterpret_cast<const f16x8*>(&Ah[32 * wm + 16 + lrow][lk]);
    f16x8 al0 = *reinterpret_cast<const f16x8*>(&Al[32 * wm + lrow][lk]);
    f16x8 al1 = *reinterpret_cast<const f16x8*>(&Al[32 * wm + 16 + lrow][lk]);
    f16x8 bh0 = *reinterpret_cast<const f16x8*>(&Bh[32 * wn + lrow][lk]);
    f16x8 bh1 = *reinterpret_cast<const f16x8*>(&Bh[32 * wn + 16 + lrow][lk]);
    f16x8 bl0 = *reinterpret_cast<const f16x8*>(&Bl[32 * wn + lrow][lk]);
    f16x8 bl1 = *reinterpret_cast<const f16x8*>(&Bl[32 * wn + 16 + lrow][lk]);

    acc[0][0] = __builtin_amdgcn_mfma_f32_16x16x32_f16(ah0, bh0, acc[0][0], 0, 0, 0);
    acc[0][0] = __builtin_amdgcn_mfma_f32_16x16x32_f16(ah0, bl0, acc[0][0], 0, 0, 0);
    acc[0][0] = __builtin_amdgcn_mfma_f32_16x16x32_f16(al0, bh0, acc[0][0], 0, 0, 0);
    acc[0][1] = __builtin_amdgcn_mfma_f32_16x16x32_f16(ah0, bh1, acc[0][1], 0, 0, 0);
    acc[0][1] = __builtin_amdgcn_mfma_f32_16x16x32_f16(ah0, bl1, acc[0][1], 0, 0, 0);
    acc[0][1] = __builtin_amdgcn_mfma_f32_16x16x32_f16(al0, bh1, acc[0][1], 0, 0, 0);
    acc[1][0] = __builtin_amdgcn_mfma_f32_16x16x32_f16(ah1, bh0, acc[1][0], 0, 0, 0);
    acc[1][0] = __builtin_amdgcn_mfma_f32_16x16x32_f16(ah1, bl0, acc[1][0], 0, 0, 0);
    acc[1][0] = __builtin_amdgcn_mfma_f32_16x16x32_f16(al1, bh0, acc[1][0], 0, 0, 0);
    acc[1][1] = __builtin_amdgcn_mfma_f32_16x16x32_f16(ah1, bh1, acc[1][1], 0, 0, 0);
    acc[1][1] = __builtin_amdgcn_mfma_f32_16x16x32_f16(ah1, bl1, acc[1][1], 0, 0, 0);
    acc[1][1] = __builtin_amdgcn_mfma_f32_16x16x32_f16(al1, bh1, acc[1][1], 0, 0, 0);
    __syncthreads();
  }

#pragma unroll
  for (int am = 0; am < 2; am++) {
#pragma unroll
    for (int bn = 0; bn < 2; bn++) {
      int col = n0 + 32 * wn + 16 * bn + lrow;
      float bv = br1[col];
#pragma unroll
      for (int r = 0; r < 4; r++) {
        int rowt = 32 * wm + 16 * am + (lane >> 4) * 4 + r;
        float v = acc[am][bn][r] + bv;
        hrf[(size_t)(m0 + rowt) * H_DIM + col] = fmaxf(v, 0.f);
      }
    }
  }
}

// ---- phase-1 fused kernel: router (512) + cast_x (1024) + tcastW1 (16384) + tcastW2 (16384) ----
// sequential ranges (round-6/7 A/B: sequential >= interleaved)
#define P1_RG 512
#define P1_CX 1024
#define P1_T1 16384
#define P1_T2 16384
#define P1_TOTAL (P1_RG + P1_CX + P1_T1 + P1_T2)
__global__ __launch_bounds__(256) void fusedA_kernel(
    const float* __restrict__ x, const float* __restrict__ Wr1, const float* __restrict__ br1,
    float* __restrict__ hrf, const float* __restrict__ W1, _Float16* __restrict__ W1t,
    const float* __restrict__ W2, _Float16* __restrict__ W2t, _Float16* __restrict__ xh) {
  __shared__ __align__(16) char smem[20480];
  int bid = blockIdx.x;
  if (bid < P1_RG) {
    router_gemm1_body((bid >> 4) * 64, (bid & 15) * 64, x, Wr1, br1, hrf, smem);
  } else if (bid < P1_RG + P1_CX) {
    cast_x_body(bid - P1_RG, x, xh);
  } else if (bid < P1_RG + P1_CX + P1_T1) {
    int idx = bid - P1_RG - P1_CX;  // W1: K=H, N=F
    int nt = idx & 63, kt = (idx >> 6) & 15, e = idx >> 10;
    tcast_body(W1, W1t, H_DIM, F_DIM, e, kt * 64, nt * 64, smem);
  } else {
    int idx = bid - P1_RG - P1_CX - P1_T1;  // W2: K=F, N=H
    int nt = idx & 15, kt = (idx >> 4) & 63, e = idx >> 10;
    tcast_body(W2, W2t, F_DIM, H_DIM, e, kt * 64, nt * 64, smem);
  }
}

// logits = hrf @ Wr2 + br2 ; one wave per token (fp32)
__global__ __launch_bounds__(256) void router_logits_kernel(
    const float* __restrict__ hrf, const float* __restrict__ Wr2,
    const float* __restrict__ br2, float* __restrict__ logits) {
  int t = blockIdx.x * 4 + (threadIdx.x >> 6);
  int lane = threadIdx.x & 63;
  float acc[E_NUM];
#pragma unroll
  for (int e = 0; e < E_NUM; e++) acc[e] = 0.f;
  const float* hr = hrf + (size_t)t * H_DIM;
#pragma unroll 4
  for (int i = 0; i < H_DIM / 64; i++) {
    int k = lane + 64 * i;
    float a = hr[k];
    const floatx4* w4 = reinterpret_cast<const floatx4*>(Wr2 + (size_t)k * E_NUM);
    floatx4 w0 = w4[0], w1 = w4[1], w2 = w4[2], w3 = w4[3];
#pragma unroll
    for (int j = 0; j < 4; j++) {
      acc[j]      += a * w0[j];
      acc[4 + j]  += a * w1[j];
      acc[8 + j]  += a * w2[j];
      acc[12 + j] += a * w3[j];
    }
  }
#pragma unroll
  for (int e = 0; e < E_NUM; e++) {
    float v = acc[e];
    for (int off = 32; off > 0; off >>= 1) v += __shfl_xor(v, off);
    if (lane == e) logits[(size_t)t * E_NUM + e] = v + br2[e];
  }
}

// merged top-k + softmax + scan + tile table + scatter; one block of 1024 threads
__global__ __launch_bounds__(1024) void routing_kernel(
    const float* __restrict__ logits, int* __restrict__ offs,
    int* __restrict__ toks, float* __restrict__ wsl, int* __restrict__ stk,
    int* __restrict__ tileE, int* __restrict__ tileM, int* __restrict__ tileC) {
  __shared__ int cnt[E_NUM], cur[E_NUM], loff[E_NUM + 1];
  int tid = threadIdx.x;
  if (tid < E_NUM) { cnt[tid] = 0; cur[tid] = 0; }
  __syncthreads();
  int ti[2][K_TOP]; float tw[2][K_TOP];
#pragma unroll
  for (int u = 0; u < 2; u++) {
    int t = u * 1024 + tid;
    float lg[E_NUM];
#pragma unroll
    for (int e = 0; e < E_NUM; e++) lg[e] = logits[(size_t)t * E_NUM + e];
    unsigned int used = 0;
    float vals[K_TOP];
#pragma unroll
    for (int k = 0; k < K_TOP; k++) {
      float best = -1e30f; int bi = 0;
#pragma unroll
      for (int e = 0; e < E_NUM; e++) {
        if (!((used >> e) & 1u) && lg[e] > best) { best = lg[e]; bi = e; }
      }
      used |= (1u << bi);
      vals[k] = best; ti[u][k] = bi;
    }
    float m = vals[0], s = 0.f;
#pragma unroll
    for (int k = 0; k < K_TOP; k++) { tw[u][k] = expf(vals[k] - m); s += tw[u][k]; }
    float inv = 1.f / s;
#pragma unroll
    for (int k = 0; k < K_TOP; k++) {
      tw[u][k] *= inv;
      atomicAdd(&cnt[ti[u][k]], 1);
    }
  }
  __syncthreads();
  if (tid == 0) {
    int acc = 0;
    loff[0] = 0; offs[0] = 0;
    for (int e = 0; e < E_NUM; e++) { acc += cnt[e]; loff[e + 1] = acc; offs[e + 1] = acc; }
    int idx = 0;
    for (int e = 0; e < E_NUM; e++) {
      for (int m0 = 0; m0 < cnt[e]; m0 += 128) { tileE[idx] = e; tileM[idx] = m0; idx++; }
    }
    tileC[0] = idx;
  }
  __syncthreads();
#pragma unroll
  for (int u = 0; u < 2; u++) {
    int t = u * 1024 + tid;
#pragma unroll
    for (int k = 0; k < K_TOP; k++) {
      int e = ti[u][k];
      int pos = atomicAdd(&cur[e], 1);
      int slot = loff[e] + pos;
      toks[slot] = t;
      wsl[slot] = tw[u][k];
      stk[t * K_TOP + k] = slot;
    }
  }
}

// out[t][h] = sum_k ybuf[stk[t][k]][h] ; ybuf f16
__global__ void combine_kernel(const _Float16* __restrict__ ybuf, const int* __restrict__ stk,
                               float* __restrict__ out) {
  int i = blockIdx.x * 256 + threadIdx.x;
  size_t p = (size_t)i * 8;
  int t = (int)(p >> 10);
  int h = (int)(p & 1023);
  float s[8] = {0.f, 0.f, 0.f, 0.f, 0.f, 0.f, 0.f, 0.f};
#pragma unroll
  for (int k = 0; k < K_TOP; k++) {
    int slot = stk[t * K_TOP + k];
    f16x8 v = *reinterpret_cast<const f16x8*>(ybuf + (size_t)slot * H_DIM + h);
#pragma unroll
    for (int j = 0; j < 8; j++) s[j] += (float)v[j];
  }
  floatx4 o0 = {s[0], s[1], s[2], s[3]};
  floatx4 o1 = {s[4], s[5], s[6], s[7]};
  *reinterpret_cast<floatx4*>(out + p) = o0;
  *reinterpret_cast<floatx4*>(out + p + 4) = o1;
}

// ---------------- expert GEMM body: 128x128, 3-buffer counted-vmcnt, swizzled LDS ----------
template <int KK, int ACT, bool GATHER, bool SCALE>
__device__ __forceinline__ void moe_gemm_body(
    int ti, int n0, const _Float16* __restrict__ A, const _Float16* __restrict__ Bt,
    const float* __restrict__ bias, _Float16* __restrict__ Out,
    const int* __restrict__ offsets, const int* __restrict__ toklist,
    const float* __restrict__ wslot, const int* __restrict__ tileE,
    const int* __restrict__ tileM, const int* __restrict__ tileC,
    int N, char* smem) {
  if (ti >= tileC[0]) return;
  const int K = KK;
  int e = tileE[ti], m0 = tileM[ti];
  int base = offsets[e], cnt = offsets[e + 1] - base;

  _Float16 (*As)[128][32] = reinterpret_cast<_Float16(*)[128][32]>(smem);
  _Float16 (*Bs)[128][32] = reinterpret_cast<_Float16(*)[128][32]>(smem + 24576);

  int tid = threadIdx.x;
  int w = tid >> 6, lane = tid & 63;
  int wm = w >> 1, wn = w & 1;
  int lrow = lane & 15;

  int ar0 = w * 32 + (lane >> 2);
  int ar1 = ar0 + 16;
  int ach = (((lane & 3) ^ ((lane >> 3) & 3))) * 8;
  int mr0 = m0 + ar0; if (mr0 >= cnt) mr0 = cnt - 1;
  int mr1 = m0 + ar1; if (mr1 >= cnt) mr1 = cnt - 1;
  const _Float16* gA0 = A + (long)(GATHER ? toklist[base + mr0] : (base + mr0)) * K + ach;
  const _Float16* gA1 = A + (long)(GATHER ? toklist[base + mr1] : (base + mr1)) * K + ach;
  const _Float16* bge = Bt + (size_t)e * N * K;
  const _Float16* gB0 = bge + (long)(n0 + ar0) * K + ach;
  const _Float16* gB1 = bge + (long)(n0 + ar1) * K + ach;

  int phys8 = ((lane >> 4) ^ ((lrow >> 1) & 3)) * 8;

#define STAGE3(buf, kk) do { \
    gload16(gA0 + (kk), &As[buf][w * 32][0]); \
    gload16(gA1 + (kk), &As[buf][w * 32 + 16][0]); \
    gload16(gB0 + (kk), &Bs[buf][w * 32][0]); \
    gload16(gB1 + (kk), &Bs[buf][w * 32 + 16][0]); \
  } while (0)

#define COMPUTE3(buf) do { \
    f16x8 a[4], b[4]; \
    _Pragma("unroll") \
    for (int i = 0; i < 4; i++) { \
      a[i] = *reinterpret_cast<const f16x8*>(&As[buf][wm * 64 + i * 16 + lrow][phys8]); \
      b[i] = *reinterpret_cast<const f16x8*>(&Bs[buf][wn * 64 + i * 16 + lrow][phys8]); \
    } \
    __builtin_amdgcn_s_setprio(1); \
    _Pragma("unroll") \
    for (int i = 0; i < 4; i++) \
      _Pragma("unroll") \
      for (int j = 0; j < 4; j++) \
        acc[i][j] = __builtin_amdgcn_mfma_f32_16x16x32_f16(a[i], b[j], acc[i][j], 0, 0, 0); \
    __builtin_amdgcn_s_setprio(0); \
  } while (0)

  floatx4 acc[4][4];
#pragma unroll
  for (int i = 0; i < 4; i++)
#pragma unroll
    for (int j = 0; j < 4; j++) acc[i][j] = (floatx4){0.f, 0.f, 0.f, 0.f};

  constexpr int nk = KK / 32;
  STAGE3(0, 0);
  STAGE3(1, 32);

#pragma unroll 3
  for (int it = 0; it < nk - 1; ++it) {
    asm volatile("s_waitcnt vmcnt(4)" ::: "memory");
    __builtin_amdgcn_s_barrier();
    if (it + 2 < nk) STAGE3((it + 2) % 3, (it + 2) * 32);
    COMPUTE3(it % 3);
  }
  asm volatile("s_waitcnt vmcnt(0)" ::: "memory");
  __builtin_amdgcn_s_barrier();
  COMPUTE3((nk - 1) % 3);

#undef STAGE3
#undef COMPUTE3

  const float* be = bias + (size_t)e * N;
#pragma unroll
  for (int fm = 0; fm < 4; fm++) {
#pragma unroll
    for (int fn = 0; fn < 4; fn++) {
      int col = n0 + wn * 64 + fn * 16 + lrow;
      float bv = be[col];
#pragma unroll
      for (int r = 0; r < 4; r++) {
        int rowt = wm * 64 + fm * 16 + (lane >> 4) * 4 + r;
        int mg = m0 + rowt;
        if (mg < cnt) {
          float v = acc[fm][fn][r] + bv;
          if (ACT == 2) v = gelu_fast(v);
          long orow = base + mg;
          if (SCALE) v *= wslot[orow];
          Out[orow * (long)N + col] = (_Float16)v;
        }
      }
    }
  }
}

// expert GEMM1 standalone (K=1024): hbuf = gelu(x[tok] @ W1t^T + b1)
__global__ __launch_bounds__(256) void moe_gemm1_kernel(
    const _Float16* __restrict__ xh, const _Float16* __restrict__ W1t,
    const float* __restrict__ b1, _Float16* __restrict__ hbuf,
    const int* __restrict__ offsets, const int* __restrict__ toklist,
    const int* __restrict__ tileE, const int* __restrict__ tileM, const int* __restrict__ tileC) {
  __shared__ __align__(16) char smem[49152];
  moe_gemm_body<H_DIM, 2, true, false>(blockIdx.y, blockIdx.x * 128, xh, W1t, b1, hbuf,
                                       offsets, toklist, nullptr, tileE, tileM, tileC,
                                       F_DIM, smem);
}

// expert GEMM2 standalone (K=4096), f16 out with combine-weight scale
__global__ __launch_bounds__(256) void moe_gemm2_kernel(
    const _Float16* __restrict__ hbuf, const _Float16* __restrict__ W2t,
    const float* __restrict__ b2, _Float16* __restrict__ ybuf,
    const int* __restrict__ offsets, const float* __restrict__ wslot,
    const int* __restrict__ tileE, const int* __restrict__ tileM, const int* __restrict__ tileC) {
  __shared__ __align__(16) char smem[49152];
  moe_gemm_body<F_DIM, 0, false, true>(blockIdx.y, blockIdx.x * 128, hbuf, W2t, b2, ybuf,
                                       offsets, nullptr, wslot, tileE, tileM, tileC,
                                       H_DIM, smem);
}

// ---------------- FALLBACK MFMA GEMM (in-flight convert, small ws) ----------------
template <int ACT, bool GATHER, bool OFFS, bool SCALE>
__global__ __launch_bounds__(256) void moe_gemm(
    const _Float16* __restrict__ A, const float* __restrict__ W,
    const float* __restrict__ bias, _Float16* __restrict__ Out,
    const int* __restrict__ offsets, const int* __restrict__ toklist,
    const float* __restrict__ wslot, int M, int N, int K) {
  int e = blockIdx.z;
  int base = 0, cnt = M;
  if (OFFS) { base = offsets[e]; cnt = offsets[e + 1] - base; }
  int m0 = blockIdx.y * 64;
  if (m0 >= cnt) return;
  int n0 = blockIdx.x * 64;
  const float* We = W + (size_t)e * K * N;
  const float* be = bias + (size_t)e * N;

  __shared__ _Float16 As[64][40];
  __shared__ _Float16 Bs[64][40];

  int tid = threadIdx.x;
  int arow = tid >> 2, achk = tid & 3;
  int am_idx = m0 + arow; if (am_idx > cnt - 1) am_idx = cnt - 1;
  long arowg = GATHER ? (long)toklist[base + am_idx] : (long)(base + am_idx);
  const _Float16* Arow = A + arowg * (long)K + achk * 8;

  int brow = tid >> 3, bq = tid & 7;

  floatx4 acc[2][2];
#pragma unroll
  for (int i = 0; i < 2; i++)
#pragma unroll
    for (int j = 0; j < 2; j++) acc[i][j] = (floatx4){0.f, 0.f, 0.f, 0.f};

  int wv = tid >> 6, lane = tid & 63;
  int wm = wv >> 1, wn = wv & 1;
  int lrow = lane & 15, lk = (lane >> 4) * 8;

  for (int k0 = 0; k0 < K; k0 += 32) {
    *reinterpret_cast<f16x8*>(&As[arow][achk * 8]) = *reinterpret_cast<const f16x8*>(Arow + k0);
    const float* wp = We + (size_t)(k0 + brow) * N + n0 + bq * 4;
    floatx4 w0 = *reinterpret_cast<const floatx4*>(wp);
    floatx4 w1 = *reinterpret_cast<const floatx4*>(wp + 32);
#pragma unroll
    for (int i = 0; i < 4; i++) {
      Bs[bq * 4 + i][brow]      = (_Float16)w0[i];
      Bs[32 + bq * 4 + i][brow] = (_Float16)w1[i];
    }
    __syncthreads();

    f16x8 a0 = *reinterpret_cast<const f16x8*>(&As[32 * wm + lrow][lk]);
    f16x8 a1 = *reinterpret_cast<const f16x8*>(&As[32 * wm + 16 + lrow][lk]);
    f16x8 b0 = *reinterpret_cast<const f16x8*>(&Bs[32 * wn + lrow][lk]);
    f16x8 b1 = *reinterpret_cast<const f16x8*>(&Bs[32 * wn + 16 + lrow][lk]);
    acc[0][0] = __builtin_amdgcn_mfma_f32_16x16x32_f16(a0, b0, acc[0][0], 0, 0, 0);
    acc[0][1] = __builtin_amdgcn_mfma_f32_16x16x32_f16(a0, b1, acc[0][1], 0, 0, 0);
    acc[1][0] = __builtin_amdgcn_mfma_f32_16x16x32_f16(a1, b0, acc[1][0], 0, 0, 0);
    acc[1][1] = __builtin_amdgcn_mfma_f32_16x16x32_f16(a1, b1, acc[1][1], 0, 0, 0);
    __syncthreads();
  }

#pragma unroll
  for (int am = 0; am < 2; am++) {
#pragma unroll
    for (int bn = 0; bn < 2; bn++) {
      int col = n0 + 32 * wn + 16 * bn + lrow;
      float bv = be[col];
#pragma unroll
      for (int r = 0; r < 4; r++) {
        int rowt = 32 * wm + 16 * am + (lane >> 4) * 4 + r;
        int mg = m0 + rowt;
        if (mg < cnt) {
          float v = acc[am][bn][r] + bv;
          if (ACT == 2) v = gelu_fast(v);
          long orow = base + mg;
          if (SCALE) v *= wslot[orow];
          Out[orow * (long)N + col] = (_Float16)v;
        }
      }
    }
  }
}

__global__ void cast_x_kernel(const float* __restrict__ x, _Float16* __restrict__ xh) {
  cast_x_body(blockIdx.x, x, xh);
}

__global__ __launch_bounds__(256) void router_gemm1_kernel(
    const float* __restrict__ x, const float* __restrict__ Wr1,
    const float* __restrict__ br1, float* __restrict__ hrf) {
  __shared__ __align__(16) char smem[20480];
  router_gemm1_body(blockIdx.y * 64, blockIdx.x * 64, x, Wr1, br1, hrf, smem);
}

// ---------------- launch ----------------
extern "C" void kernel_launch(void* const* d_in, const int* in_sizes, int n_in,
                              void* d_out, int out_size, void* d_ws, size_t ws_size,
                              hipStream_t stream) {
  const float* x   = (const float*)d_in[0];
  const float* Wr1 = (const float*)d_in[1];
  const float* br1 = (const float*)d_in[2];
  const float* Wr2 = (const float*)d_in[3];
  const float* br2 = (const float*)d_in[4];
  const float* W1  = (const float*)d_in[5];
  const float* b1  = (const float*)d_in[6];
  const float* W2  = (const float*)d_in[7];
  const float* b2  = (const float*)d_in[8];
  float* out = (float*)d_out;

  char* ws = (char*)d_ws;
  float* logits = (float*)(ws + LOGIT_OFF);
  int*   offs   = (int*)(ws + OFFS_OFF);
  int*   toks   = (int*)(ws + TOKS_OFF);
  float* wsl    = (float*)(ws + WSL_OFF);
  int*   stk    = (int*)(ws + STK_OFF);
  int*   tileE  = (int*)(ws + TILEE_OFF);
  int*   tileM  = (int*)(ws + TILEM_OFF);
  int*   tileC  = (int*)(ws + TILEC_OFF);
  _Float16* xh   = (_Float16*)(ws + XH_OFF);
  float*    hrf  = (float*)(ws + HBUF_OFF);
  _Float16* hbuf = (_Float16*)(ws + HBUF_OFF);
  _Float16* ybuf = (_Float16*)(ws + YBUF_OFF);
  _Float16* W1t  = (_Float16*)(ws + W1T_OFF);
  _Float16* W2t  = (_Float16*)(ws + W2T_OFF);

  bool fast = ws_size >= WS_NEED_FAST;

  if (fast) {
    // phase 1: everything with no routing dependency (router GEMM + x-cast + BOTH weight tcasts)
    fusedA_kernel<<<P1_TOTAL, 256, 0, stream>>>(x, Wr1, br1, hrf, W1, W1t, W2, W2t, xh);
  } else {
    cast_x_kernel<<<(T_TOK * H_DIM / 8) / 256, 256, 0, stream>>>(x, xh);
    router_gemm1_kernel<<<dim3(H_DIM / 64, T_TOK / 64), 256, 0, stream>>>(x, Wr1, br1, hrf);
  }

  router_logits_kernel<<<T_TOK / 4, 256, 0, stream>>>(hrf, Wr2, br2, logits);
  routing_kernel<<<1, 1024, 0, stream>>>(logits, offs, toks, wsl, stk, tileE, tileM, tileC);

  if (fast) {
    moe_gemm1_kernel<<<dim3(F_DIM / 128, 80), 256, 0, stream>>>(xh, W1t, b1, hbuf, offs, toks,
                                                                tileE, tileM, tileC);
    moe_gemm2_kernel<<<dim3(H_DIM / 128, 80), 256, 0, stream>>>(hbuf, W2t, b2, ybuf, offs, wsl,
                                                                tileE, tileM, tileC);
  } else {
    moe_gemm<2, true, true, false><<<dim3(F_DIM / 64, T_TOK / 64, E_NUM), 256, 0, stream>>>(
        xh, W1, b1, hbuf, offs, toks, nullptr, T_TOK, F_DIM, H_DIM);
    moe_gemm<0, false, true, true><<<dim3(H_DIM / 64, T_TOK / 64, E_NUM), 256, 0, stream>>>(
        hbuf, W2, b2, ybuf, offs, nullptr, wsl, T_TOK, H_DIM, F_DIM);
  }

  combine_kernel<<<(T_TOK * H_DIM / 8) / 256, 256, 0, stream>>>(ybuf, stk, out);
}